// Round 9
// baseline (235.107 us; speedup 1.0000x reference)
//
#include <hip/hip_runtime.h>

#define NN 50000
#define EE 200000
#define RR 4
#define SC_TOTAL (RR * NN)                 // 200000 segments
#define CAP 32                             // max in-degree per (node,etype); P(exceed)~1e-19
#define GTILE ((NN + 127) / 128)           // 391 row-panels of 128
#define NB_F  1563                         // fill chunks (512 edges each, 2/thread)
#define NB_TOT (GTILE + NB_F)              // 1954; gemm if bid%5==0

typedef __attribute__((ext_vector_type(8))) short bf16x8;
typedef __attribute__((ext_vector_type(4))) float f32x4;

__device__ inline unsigned short f2bf(float x) {   // round-to-nearest-even
    unsigned int u = __float_as_uint(x);
    u += 0x7fffu + ((u >> 16) & 1u);
    return (unsigned short)(u >> 16);
}
__device__ inline unsigned pk2(float a, float b) {
    return (unsigned)f2bf(a) | ((unsigned)f2bf(b) << 16);
}
__device__ inline float bflo(unsigned u) { return __uint_as_float(u << 16); }
__device__ inline float bfhi(unsigned u) { return __uint_as_float(u & 0xffff0000u); }

// ---------------------------------------------------------------------------
// init (small): W1T [0,256) | W2T [256,384) | btab1 [384,392) |
// btab2 [392,396) | cnt zero [396,592).  No featb pass (gemm1 converts inline).
// W layouts are TRANSFORM-FIRST concat: WT[jout][k], jout = r*ON + j.
__global__ __launch_bounds__(256) void init_kernel(
    const float* __restrict__ W1, const float* __restrict__ b1,
    const float* __restrict__ W2, const float* __restrict__ b2,
    unsigned short* __restrict__ W1T, unsigned short* __restrict__ W2T,
    float* __restrict__ btab1, float* __restrict__ btab2,
    int* __restrict__ cnt)
{
    int b = blockIdx.x, t = threadIdx.x;
    if (b < 256) {
        // W1T[(r*128+j)*128 + k] = W1[r,k,j];  i in [0,65536)
        int i = b * 256 + t;
        int jout = i >> 7, k = i & 127;
        int r = jout >> 7, j = jout & 127;
        W1T[i] = f2bf(W1[r * 16384 + k * 128 + j]);
    } else if (b < 384) {
        // W2T[(r*64+j)*128 + k] = W2[r,k,j];  i in [0,32768)
        int i = (b - 256) * 256 + t;
        int jout = i >> 7, k = i & 127;
        int r = jout >> 6, j = jout & 63;
        W2T[i] = f2bf(W2[r * 8192 + k * 64 + j]);
    } else if (b < 392) {
        int i = (b - 384) * 256 + t;
        int mm = i >> 7, c = i & 127;
        float s = 0.f;
        #pragma unroll
        for (int r = 0; r < RR; ++r) if (mm & (1 << r)) s += b1[r * 128 + c];
        btab1[i] = s;
    } else if (b < 396) {
        int i = (b - 392) * 256 + t;
        int mm = i >> 6, c = i & 63;
        float s = 0.f;
        #pragma unroll
        for (int r = 0; r < RR; ++r) if (mm & (1 << r)) s += b2[r * 64 + c];
        btab2[i] = s;
    } else {
        // zero cnt: 200K ints, int4 per thread
        int i = ((b - 396) * 256 + t) * 4;
        if (i < SC_TOTAL) *(int4*)&cnt[i] = make_int4(0, 0, 0, 0);
    }
}

// ---------------------------------------------------------------------------
// FUSED fill + gemm1. bid%5==0 -> gemm panel (128 rows x 512 cols): read fp32
// feat rows ONCE, convert->swizzled LDS A (32 KB); A-frags loaded once, 4
// col-panels stream W-frags from L2-resident W1T (128 KB, no W LDS).
// Other bids -> 512-edge bucket-append chunk (TCC-bound).
__global__ __launch_bounds__(256) void fill_gemm1(
    const int* __restrict__ edges, int* __restrict__ cnt,
    unsigned short* __restrict__ ssrc2,
    const float* __restrict__ feat, const unsigned short* __restrict__ WT,
    unsigned short* __restrict__ H)
{
    __shared__ __align__(16) unsigned short Al[128 * 128];   // 32768 B (gemm path)
    const int bid = blockIdx.x;
    const int tid = threadIdx.x;

    if (bid % 5 != 0) {
        // ---- fill path: f in [0, NB_F), 2 edges/thread (independent chains)
        int f = bid - bid / 5 - 1;
        #pragma unroll
        for (int k = 0; k < 2; ++k) {
            int i = f * 512 + k * 256 + tid;
            if (i < RR * EE) {
                int r = i / EE;
                int e = i - r * EE;
                const int* es = edges + (size_t)r * 2 * EE;
                int src = es[e];
                int dst = es[EE + e];
                int seg = r * NN + dst;
                int p = atomicAdd(&cnt[seg], 1);
                if (p < CAP) ssrc2[(size_t)seg * CAP + p] = (unsigned short)src;
            }
        }
        return;
    }

    // ---- gemm path: g in [0, GTILE); row panel [row0, row0+128) x 512 cols
    const int g    = bid / 5;
    const int wv   = tid >> 6;
    const int lane = tid & 63;
    const int m    = lane & 15;
    const int q    = lane >> 4;
    const int row0 = g * 128;

    // stage A: fp32 feat -> bf16, swizzled LDS (byte ^= (row&7)<<4 within row)
    #pragma unroll
    for (int it = 0; it < 4; ++it) {
        int i  = it * 256 + tid;            // [0,1024): 128 rows x 8 chunks
        int rr = i >> 3, c16 = (i & 7) * 16;
        int row = row0 + rr;
        uint4 u01 = make_uint4(0, 0, 0, 0), u23 = make_uint4(0, 0, 0, 0);
        if (row < NN) {
            const float* fp = feat + (size_t)row * 128 + c16;
            float4 v0 = *(const float4*)(fp);
            float4 v1 = *(const float4*)(fp + 4);
            float4 v2 = *(const float4*)(fp + 8);
            float4 v3 = *(const float4*)(fp + 12);
            u01 = make_uint4(pk2(v0.x, v0.y), pk2(v0.z, v0.w),
                             pk2(v1.x, v1.y), pk2(v1.z, v1.w));
            u23 = make_uint4(pk2(v2.x, v2.y), pk2(v2.z, v2.w),
                             pk2(v3.x, v3.y), pk2(v3.z, v3.w));
        }
        int base = rr * 256 + c16 * 2;
        int sw   = (rr & 7) << 4;
        *(uint4*)((char*)Al + ((base) ^ sw))      = u01;
        *(uint4*)((char*)Al + ((base + 16) ^ sw)) = u23;
    }
    __syncthreads();

    // A-frags once: rows wv*32+m (+16), all 4 k-slices  (32 VGPR)
    bf16x8 af[2][4];
    #pragma unroll
    for (int rf = 0; rf < 2; ++rf) {
        int row = wv * 32 + rf * 16 + m;
        int sw  = (row & 7) << 4;
        #pragma unroll
        for (int kk = 0; kk < 4; ++kk)
            af[rf][kk] = *(const bf16x8*)((const char*)Al +
                             ((row * 256 + kk * 64 + q * 16) ^ sw));
    }

    // 4 col-panels of 128; B-frags streamed from L2-resident W1T
    #pragma unroll
    for (int cp = 0; cp < 4; ++cp) {
        f32x4 acc[2][8];
        #pragma unroll
        for (int rf = 0; rf < 2; ++rf)
            #pragma unroll
            for (int nt = 0; nt < 8; ++nt) acc[rf][nt] = (f32x4){0.f, 0.f, 0.f, 0.f};

        #pragma unroll
        for (int kk = 0; kk < 4; ++kk) {
            #pragma unroll
            for (int nt = 0; nt < 8; ++nt) {
                bf16x8 bfr = *(const bf16x8*)(WT +
                    (size_t)(cp * 128 + nt * 16 + m) * 128 + kk * 32 + q * 8);
                acc[0][nt] = __builtin_amdgcn_mfma_f32_16x16x32_bf16(af[0][kk], bfr, acc[0][nt], 0, 0, 0);
                acc[1][nt] = __builtin_amdgcn_mfma_f32_16x16x32_bf16(af[1][kk], bfr, acc[1][nt], 0, 0, 0);
            }
        }

        #pragma unroll
        for (int rf = 0; rf < 2; ++rf) {
            #pragma unroll
            for (int rg = 0; rg < 4; ++rg) {
                int row = row0 + wv * 32 + rf * 16 + q * 4 + rg;
                if (row < NN) {
                    unsigned short* Hp = H + (size_t)row * 512 + cp * 128 + m;
                    #pragma unroll
                    for (int nt = 0; nt < 8; ++nt)
                        Hp[nt * 16] = f2bf(acc[rf][nt][rg]);
                }
            }
        }
    }
}

// ---------------------------------------------------------------------------
// transform-first GEMM (layer 2): H2[N x 256] = h1r[N x 128]_bf16 @ W2T^T.
template<int OTOT>
__global__ __launch_bounds__(256) void gemm_tf(
    const unsigned short* __restrict__ A, const unsigned short* __restrict__ WT,
    unsigned short* __restrict__ H)
{
    __shared__ __align__(16) unsigned short Wl[128 * 128];   // 32768 B, swizzled
    const int tid  = threadIdx.x;
    const int wv   = tid >> 6;
    const int lane = tid & 63;
    const int m    = lane & 15;
    const int q    = lane >> 4;
    const int col0 = blockIdx.x * 128;
    const int row0 = blockIdx.y * 128;

    #pragma unroll
    for (int i = 0; i < 8; ++i) {
        int L  = i * 4096 + tid * 16;       // linear byte in [128][256]
        int nr = L >> 8, ir = L & 255;
        uint4 v = *(const uint4*)((const char*)WT + ((size_t)(col0 + nr) << 8) + ir);
        *(uint4*)((char*)Wl + nr * 256 + (ir ^ ((nr & 7) << 4))) = v;
    }
    __syncthreads();

    f32x4 acc[2][8];
    #pragma unroll
    for (int rf = 0; rf < 2; ++rf)
        #pragma unroll
        for (int nt = 0; nt < 8; ++nt) acc[rf][nt] = (f32x4){0.f, 0.f, 0.f, 0.f};

    const int ra0 = row0 + wv * 32 + m;
    const int ra1 = ra0 + 16;
    const bool g0 = ra0 < NN, g1 = ra1 < NN;
    const unsigned short* Ap0 = A + (size_t)ra0 * 128 + q * 8;
    const unsigned short* Ap1 = A + (size_t)ra1 * 128 + q * 8;
    const bf16x8 bz = (bf16x8){0, 0, 0, 0, 0, 0, 0, 0};

    #pragma unroll
    for (int kk = 0; kk < 4; ++kk) {
        bf16x8 a0 = g0 ? *(const bf16x8*)(Ap0 + kk * 32) : bz;
        bf16x8 a1 = g1 ? *(const bf16x8*)(Ap1 + kk * 32) : bz;
        #pragma unroll
        for (int nt = 0; nt < 8; ++nt) {
            int offb = (nt * 16 + m) * 256 + ((kk * 64 + q * 16) ^ ((m & 7) << 4));
            bf16x8 bfr = *(const bf16x8*)((const char*)Wl + offb);
            acc[0][nt] = __builtin_amdgcn_mfma_f32_16x16x32_bf16(a0, bfr, acc[0][nt], 0, 0, 0);
            acc[1][nt] = __builtin_amdgcn_mfma_f32_16x16x32_bf16(a1, bfr, acc[1][nt], 0, 0, 0);
        }
    }

    #pragma unroll
    for (int rf = 0; rf < 2; ++rf) {
        #pragma unroll
        for (int rg = 0; rg < 4; ++rg) {
            int row = row0 + wv * 32 + rf * 16 + q * 4 + rg;
            if (row < NN) {
                unsigned short* Hp = H + (size_t)row * OTOT + col0 + m;
                #pragma unroll
                for (int nt = 0; nt < 8; ++nt)
                    Hp[nt * 16] = f2bf(acc[rf][nt][rg]);
            }
        }
    }
}

// ---------------------------------------------------------------------------
// gather-mean layer 1, MLP-boosted: 16 lanes/node; idx preload uint4 ->
// up to 32 independent row loads in flight; tail loop for deg>8.
__global__ __launch_bounds__(256) void gather_node1(
    const unsigned short* __restrict__ H1, const unsigned short* __restrict__ ssrc2,
    const int* __restrict__ cnt, const float* __restrict__ btab1,
    unsigned short* __restrict__ h1r)
{
    int n = blockIdx.x * 16 + (threadIdx.x >> 4);
    if (n >= NN) return;
    int l = threadIdx.x & 15;

    int   dg[RR];
    uint4 id[RR];
    #pragma unroll
    for (int r = 0; r < RR; ++r) {
        int seg = r * NN + n;
        dg[r] = cnt[seg];
        id[r] = *(const uint4*)(ssrc2 + (size_t)seg * CAP);
    }

    float ac[RR][8];
    #pragma unroll
    for (int r = 0; r < RR; ++r)
        #pragma unroll
        for (int i = 0; i < 8; ++i) ac[r][i] = 0.f;

    #pragma unroll
    for (int j = 0; j < 8; ++j) {
        #pragma unroll
        for (int r = 0; r < RR; ++r) {
            if (j < dg[r]) {
                unsigned w = (j >> 1) == 0 ? id[r].x : (j >> 1) == 1 ? id[r].y
                           : (j >> 1) == 2 ? id[r].z : id[r].w;
                unsigned s = (j & 1) ? (w >> 16) : (w & 0xffffu);
                uint4 u = *(const uint4*)(H1 + r * 128 + l * 8 + (size_t)s * 512);
                ac[r][0] += bflo(u.x); ac[r][1] += bfhi(u.x);
                ac[r][2] += bflo(u.y); ac[r][3] += bfhi(u.y);
                ac[r][4] += bflo(u.z); ac[r][5] += bfhi(u.z);
                ac[r][6] += bflo(u.w); ac[r][7] += bfhi(u.w);
            }
        }
    }
    if ((dg[0] | dg[1] | dg[2] | dg[3]) > 8) {
        #pragma unroll
        for (int r = 0; r < RR; ++r) {
            int nd = dg[r] < CAP ? dg[r] : CAP;
            for (int j = 8; j < nd; ++j) {
                unsigned s = ssrc2[(size_t)(r * NN + n) * CAP + j];
                uint4 u = *(const uint4*)(H1 + r * 128 + l * 8 + (size_t)s * 512);
                ac[r][0] += bflo(u.x); ac[r][1] += bfhi(u.x);
                ac[r][2] += bflo(u.y); ac[r][3] += bfhi(u.y);
                ac[r][4] += bflo(u.z); ac[r][5] += bfhi(u.z);
                ac[r][6] += bflo(u.w); ac[r][7] += bfhi(u.w);
            }
        }
    }

    int mk = (dg[0] > 0 ? 1 : 0) | (dg[1] > 0 ? 2 : 0) |
             (dg[2] > 0 ? 4 : 0) | (dg[3] > 0 ? 8 : 0);
    float iv[RR];
    #pragma unroll
    for (int r = 0; r < RR; ++r) iv[r] = dg[r] > 0 ? 1.0f / (float)dg[r] : 0.f;

    const float* bt = btab1 + mk * 128 + l * 8;
    float4 t0 = *(const float4*)bt;
    float4 t1 = *(const float4*)(bt + 4);
    float o0[8] = {t0.x, t0.y, t0.z, t0.w, t1.x, t1.y, t1.z, t1.w};
    #pragma unroll
    for (int i = 0; i < 8; ++i) {
        #pragma unroll
        for (int r = 0; r < RR; ++r) o0[i] += ac[r][i] * iv[r];
        o0[i] = fmaxf(o0[i], 0.f);
    }
    uint4 o;
    o.x = pk2(o0[0], o0[1]);
    o.y = pk2(o0[2], o0[3]);
    o.z = pk2(o0[4], o0[5]);
    o.w = pk2(o0[6], o0[7]);
    *(uint4*)&h1r[(size_t)n * 128 + l * 8] = o;
}

// ---------------------------------------------------------------------------
// gather-mean layer 2, MLP-boosted: 8 lanes/node, 128B rows (r*64 cols);
// idx preload as uint4; sum across etypes + btab2[mk] -> out [N,64] fp32.
__global__ __launch_bounds__(256) void gather_node2(
    const unsigned short* __restrict__ H2, const unsigned short* __restrict__ ssrc2,
    const int* __restrict__ cnt, const float* __restrict__ btab2,
    float* __restrict__ out)
{
    int n = blockIdx.x * 32 + (threadIdx.x >> 3);
    if (n >= NN) return;
    int l = threadIdx.x & 7;

    int   dg[RR];
    uint4 id[RR];
    #pragma unroll
    for (int r = 0; r < RR; ++r) {
        int seg = r * NN + n;
        dg[r] = cnt[seg];
        id[r] = *(const uint4*)(ssrc2 + (size_t)seg * CAP);
    }

    float ac[RR][8];
    #pragma unroll
    for (int r = 0; r < RR; ++r)
        #pragma unroll
        for (int i = 0; i < 8; ++i) ac[r][i] = 0.f;

    #pragma unroll
    for (int j = 0; j < 8; ++j) {
        #pragma unroll
        for (int r = 0; r < RR; ++r) {
            if (j < dg[r]) {
                unsigned w = (j >> 1) == 0 ? id[r].x : (j >> 1) == 1 ? id[r].y
                           : (j >> 1) == 2 ? id[r].z : id[r].w;
                unsigned s = (j & 1) ? (w >> 16) : (w & 0xffffu);
                uint4 u = *(const uint4*)(H2 + r * 64 + l * 8 + (size_t)s * 256);
                ac[r][0] += bflo(u.x); ac[r][1] += bfhi(u.x);
                ac[r][2] += bflo(u.y); ac[r][3] += bfhi(u.y);
                ac[r][4] += bflo(u.z); ac[r][5] += bfhi(u.z);
                ac[r][6] += bflo(u.w); ac[r][7] += bfhi(u.w);
            }
        }
    }
    if ((dg[0] | dg[1] | dg[2] | dg[3]) > 8) {
        #pragma unroll
        for (int r = 0; r < RR; ++r) {
            int nd = dg[r] < CAP ? dg[r] : CAP;
            for (int j = 8; j < nd; ++j) {
                unsigned s = ssrc2[(size_t)(r * NN + n) * CAP + j];
                uint4 u = *(const uint4*)(H2 + r * 64 + l * 8 + (size_t)s * 256);
                ac[r][0] += bflo(u.x); ac[r][1] += bfhi(u.x);
                ac[r][2] += bflo(u.y); ac[r][3] += bfhi(u.y);
                ac[r][4] += bflo(u.z); ac[r][5] += bfhi(u.z);
                ac[r][6] += bflo(u.w); ac[r][7] += bfhi(u.w);
            }
        }
    }

    int mk = (dg[0] > 0 ? 1 : 0) | (dg[1] > 0 ? 2 : 0) |
             (dg[2] > 0 ? 4 : 0) | (dg[3] > 0 ? 8 : 0);
    float iv[RR];
    #pragma unroll
    for (int r = 0; r < RR; ++r) iv[r] = dg[r] > 0 ? 1.0f / (float)dg[r] : 0.f;

    const float* bt = btab2 + mk * 64 + l * 8;
    float4 t0 = *(const float4*)bt;
    float4 t1 = *(const float4*)(bt + 4);
    float o0[8] = {t0.x, t0.y, t0.z, t0.w, t1.x, t1.y, t1.z, t1.w};
    #pragma unroll
    for (int i = 0; i < 8; ++i)
        #pragma unroll
        for (int r = 0; r < RR; ++r) o0[i] += ac[r][i] * iv[r];

    float* op = out + (size_t)n * 64 + l * 8;
    *(float4*)op       = make_float4(o0[0], o0[1], o0[2], o0[3]);
    *(float4*)(op + 4) = make_float4(o0[4], o0[5], o0[6], o0[7]);
}

// ---------------------------------------------------------------------------
extern "C" void kernel_launch(void* const* d_in, const int* in_sizes, int n_in,
                              void* d_out, int out_size, void* d_ws, size_t ws_size,
                              hipStream_t stream)
{
    const float* feat  = (const float*)d_in[0];   // [N,128]
    const float* W1    = (const float*)d_in[1];   // [R,128,128]
    const float* b1    = (const float*)d_in[2];   // [R,128]
    const float* W2    = (const float*)d_in[3];   // [R,128,64]
    const float* b2    = (const float*)d_in[4];   // [R,64]
    const int*   edges = (const int*)d_in[5];     // [R,2,E]
    float* out = (float*)d_out;                   // [N,64] fp32

    char* p = (char*)d_ws;
    auto alloc = [&](size_t bytes) { char* q = p; p += (bytes + 255) & ~(size_t)255; return q; };
    int* cnt                 = (int*)alloc((size_t)SC_TOTAL * 4);                  // 0.8MB
    unsigned short* ssrc2    = (unsigned short*)alloc((size_t)SC_TOTAL * CAP * 2); // 12.8MB
    unsigned short* W1T      = (unsigned short*)alloc((size_t)512 * 128 * 2);
    unsigned short* W2T      = (unsigned short*)alloc((size_t)256 * 128 * 2);
    float* btab1             = (float*)alloc((size_t)16 * 128 * 4);
    float* btab2             = (float*)alloc((size_t)16 * 64 * 4);
    unsigned short* h1r      = (unsigned short*)alloc((size_t)NN * 128 * 2);   // 12.8MB
    unsigned short* H        = (unsigned short*)alloc((size_t)NN * 512 * 2);   // 51.2MB (H1; reused as H2)

    // 1: weight prep + zero cnt (featb pass eliminated; gemm1 converts inline)
    init_kernel<<<592, 256, 0, stream>>>(W1, b1, W2, b2,
                                         W1T, W2T, btab1, btab2, cnt);
    // 2: FUSED bucket-append + H1 = feat @ W1cat (A read fp32 ONCE per panel,
    //    staged via LDS; W streamed from L2)
    fill_gemm1<<<NB_TOT, 256, 0, stream>>>(edges, cnt, ssrc2, feat, W1T, H);
    // 3: h1 = relu(sum_r mean_r(H1 slices) + btab1[mk])  [N,128] bf16
    gather_node1<<<(NN + 15) / 16, 256, 0, stream>>>(H, ssrc2, cnt, btab1, h1r);
    // 4: H2 = h1 @ W2cat  [N,256]  (overwrites H; H1 no longer needed)
    gemm_tf<256><<<dim3(2, GTILE), 256, 0, stream>>>(h1r, W2T, H);
    // 5: out = sum_r mean_r(H2 slices) + btab2[mk]  [N,64] fp32
    gather_node2<<<(NN + 31) / 32, 256, 0, stream>>>(H, ssrc2, cnt, btab2, out);
}

// Round 10
// 229.864 us; speedup vs baseline: 1.0228x; 1.0228x over previous
//
#include <hip/hip_runtime.h>

#define NN 50000
#define EE 200000
#define RR 4
#define SC_TOTAL (RR * NN)                 // 200000 segments
#define CAP 32                             // max in-degree per (node,etype); P(exceed)~1e-19
#define GTILE ((NN + 127) / 128)           // 391 row-tiles of 128 for gemm1
#define NB_G1 (4 * GTILE)                  // 1564 gemm1 tiles (512 cols)
#define NB_F  1563                         // fill chunks (512 edges each, 2/thread)

typedef __attribute__((ext_vector_type(8))) short bf16x8;
typedef __attribute__((ext_vector_type(4))) float f32x4;

__device__ inline unsigned short f2bf(float x) {   // round-to-nearest-even
    unsigned int u = __float_as_uint(x);
    u += 0x7fffu + ((u >> 16) & 1u);
    return (unsigned short)(u >> 16);
}
__device__ inline unsigned pk2(float a, float b) {
    return (unsigned)f2bf(a) | ((unsigned)f2bf(b) << 16);
}
__device__ inline float bflo(unsigned u) { return __uint_as_float(u << 16); }
__device__ inline float bfhi(unsigned u) { return __uint_as_float(u & 0xffff0000u); }

// ---------------------------------------------------------------------------
// init (R5 form): featb [0,6250) | W1T [6250,6506) | W2T [6506,6634) |
// btab1 [6634,6642) | btab2 [6642,6646) | cnt zero [6646,6842).
// W layouts are TRANSFORM-FIRST concat: WT[jout][k], jout = r*ON + j.
__global__ __launch_bounds__(256) void init_kernel(
    const float* __restrict__ feat, unsigned short* __restrict__ featb,
    const float* __restrict__ W1, const float* __restrict__ b1,
    const float* __restrict__ W2, const float* __restrict__ b2,
    unsigned short* __restrict__ W1T, unsigned short* __restrict__ W2T,
    float* __restrict__ btab1, float* __restrict__ btab2,
    int* __restrict__ cnt)
{
    int b = blockIdx.x, t = threadIdx.x;
    if (b < 6250) {
        int i = (b * 256 + t) * 4;
        float4 v = *(const float4*)&feat[i];
        *(uint2*)&featb[i] = make_uint2(pk2(v.x, v.y), pk2(v.z, v.w));
    } else if (b < 6506) {
        // W1T[(r*128+j)*128 + k] = W1[r,k,j];  i in [0,65536)
        int i = (b - 6250) * 256 + t;
        int jout = i >> 7, k = i & 127;
        int r = jout >> 7, j = jout & 127;
        W1T[i] = f2bf(W1[r * 16384 + k * 128 + j]);
    } else if (b < 6634) {
        // W2T[(r*64+j)*128 + k] = W2[r,k,j];  i in [0,32768)
        int i = (b - 6506) * 256 + t;
        int jout = i >> 7, k = i & 127;
        int r = jout >> 6, j = jout & 63;
        W2T[i] = f2bf(W2[r * 8192 + k * 64 + j]);
    } else if (b < 6642) {
        int i = (b - 6634) * 256 + t;
        int mm = i >> 7, c = i & 127;
        float s = 0.f;
        #pragma unroll
        for (int r = 0; r < RR; ++r) if (mm & (1 << r)) s += b1[r * 128 + c];
        btab1[i] = s;
    } else if (b < 6646) {
        int i = (b - 6642) * 256 + t;
        int mm = i >> 6, c = i & 63;
        float s = 0.f;
        #pragma unroll
        for (int r = 0; r < RR; ++r) if (mm & (1 << r)) s += b2[r * 64 + c];
        btab2[i] = s;
    } else {
        // zero cnt: 200K ints, int4 per thread
        int i = ((b - 6646) * 256 + t) * 4;
        if (i < SC_TOTAL) *(int4*)&cnt[i] = make_int4(0, 0, 0, 0);
    }
}

// ---------------------------------------------------------------------------
// FUSED fill + gemm1 (R5 exact, VGPR-lean gemm role). Even blocks: one
// 128x128 tile of H1 = featb @ W1cat (W LDS-swizzled). Odd blocks: 512-edge
// bucket-append chunk (TCC-bound). 1:1 interleave.
__global__ __launch_bounds__(256) void fill_gemm1(
    const int* __restrict__ edges, int* __restrict__ cnt,
    unsigned short* __restrict__ ssrc2,
    const unsigned short* __restrict__ A, const unsigned short* __restrict__ WT,
    unsigned short* __restrict__ H)
{
    __shared__ __align__(16) unsigned short Wl[128 * 128];   // 32768 B (gemm path)
    const int bid = blockIdx.x;
    const int tid = threadIdx.x;

    if (bid & 1) {
        // ---- fill path: f in [0, NB_F), 2 edges/thread (independent chains)
        int f = bid >> 1;
        #pragma unroll
        for (int k = 0; k < 2; ++k) {
            int i = f * 512 + k * 256 + tid;
            if (i < RR * EE) {
                int r = i / EE;
                int e = i - r * EE;
                const int* es = edges + (size_t)r * 2 * EE;
                int src = es[e];
                int dst = es[EE + e];
                int seg = r * NN + dst;
                int p = atomicAdd(&cnt[seg], 1);
                if (p < CAP) ssrc2[(size_t)seg * CAP + p] = (unsigned short)src;
            }
        }
        return;
    }

    // ---- gemm path: g in [0, NB_G1); tile (col0, row0), OTOT=512
    const int g    = bid >> 1;
    const int wv   = tid >> 6;
    const int lane = tid & 63;
    const int m    = lane & 15;
    const int q    = lane >> 4;
    const int col0 = (g & 3) * 128;
    const int row0 = (g >> 2) * 128;

    // stage W panel once: linear global read, swizzled LDS write
    #pragma unroll
    for (int i = 0; i < 8; ++i) {
        int L  = i * 4096 + tid * 16;       // linear byte in [128][256]
        int nr = L >> 8, ir = L & 255;
        uint4 v = *(const uint4*)((const char*)WT + ((size_t)(col0 + nr) << 8) + ir);
        *(uint4*)((char*)Wl + nr * 256 + (ir ^ ((nr & 7) << 4))) = v;
    }
    __syncthreads();

    f32x4 acc[2][8];
    #pragma unroll
    for (int rf = 0; rf < 2; ++rf)
        #pragma unroll
        for (int nt = 0; nt < 8; ++nt) acc[rf][nt] = (f32x4){0.f, 0.f, 0.f, 0.f};

    const int ra0 = row0 + wv * 32 + m;
    const int ra1 = ra0 + 16;
    const bool g0 = ra0 < NN, g1 = ra1 < NN;
    const unsigned short* Ap0 = A + (size_t)ra0 * 128 + q * 8;
    const unsigned short* Ap1 = A + (size_t)ra1 * 128 + q * 8;
    const bf16x8 bz = (bf16x8){0, 0, 0, 0, 0, 0, 0, 0};

    #pragma unroll
    for (int kk = 0; kk < 4; ++kk) {
        bf16x8 a0 = g0 ? *(const bf16x8*)(Ap0 + kk * 32) : bz;
        bf16x8 a1 = g1 ? *(const bf16x8*)(Ap1 + kk * 32) : bz;
        #pragma unroll
        for (int nt = 0; nt < 8; ++nt) {
            int offb = (nt * 16 + m) * 256 + ((kk * 64 + q * 16) ^ ((m & 7) << 4));
            bf16x8 bfr = *(const bf16x8*)((const char*)Wl + offb);
            acc[0][nt] = __builtin_amdgcn_mfma_f32_16x16x32_bf16(a0, bfr, acc[0][nt], 0, 0, 0);
            acc[1][nt] = __builtin_amdgcn_mfma_f32_16x16x32_bf16(a1, bfr, acc[1][nt], 0, 0, 0);
        }
    }

    #pragma unroll
    for (int rf = 0; rf < 2; ++rf) {
        #pragma unroll
        for (int rg = 0; rg < 4; ++rg) {
            int row = row0 + wv * 32 + rf * 16 + q * 4 + rg;
            if (row < NN) {
                unsigned short* Hp = H + (size_t)row * 512 + col0 + m;
                #pragma unroll
                for (int nt = 0; nt < 8; ++nt)
                    Hp[nt * 16] = f2bf(acc[rf][nt][rg]);
            }
        }
    }
}

// ---------------------------------------------------------------------------
// FUSED gather1 + gemm2, BLOCK-LOCAL via LDS (not per-lane regs — R8's VGPR
// mistake). Block = 64 nodes. Phase 1: R5's gather body (16 lanes/node,
// 16 nodes/pass x 4 passes) -> relu(mean+btab1) -> bf16 -> swizzled LDS
// A-tile (16 KB). Barrier. Phase 2: lean MFMA 64x256 = A @ W2cat^T, B-frags
// streamed from L2-resident W2T (64 KB). H2 is a SEPARATE buffer (no race).
__global__ __launch_bounds__(256) void gather_gemm2(
    const unsigned short* __restrict__ H1, const unsigned short* __restrict__ ssrc2,
    const int* __restrict__ cnt, const float* __restrict__ btab1,
    const unsigned short* __restrict__ W2T, unsigned short* __restrict__ H2)
{
    __shared__ __align__(16) unsigned short Al[64 * 128];    // 16384 B, swizzled
    const int tid = threadIdx.x;
    const int n0  = blockIdx.x * 64;

    // ---- phase 1: gather h1 rows for this block's 64 nodes
    const int l  = tid & 15;         // lane-in-node (16B chunk index)
    const int ng = tid >> 4;         // node slot 0..15
    #pragma unroll
    for (int pass = 0; pass < 4; ++pass) {
        int nl = pass * 16 + ng;     // local node 0..63
        int n  = n0 + nl;
        float a0 = 0.f, a1 = 0.f, a2 = 0.f, a3 = 0.f,
              a4 = 0.f, a5 = 0.f, a6 = 0.f, a7 = 0.f;
        int mk = 0;
        if (n < NN) {
            #pragma unroll
            for (int r = 0; r < RR; ++r) {
                int seg = r * NN + n;
                int deg = cnt[seg];
                if (deg <= 0) continue;
                mk |= 1 << r;
                int nd = (deg < CAP) ? deg : CAP;
                const unsigned short* lst  = ssrc2 + (size_t)seg * CAP;
                const unsigned short* base = H1 + r * 128 + l * 8;
                float b0 = 0.f, b1v = 0.f, b2v = 0.f, b3 = 0.f,
                      b4 = 0.f, b5 = 0.f, b6 = 0.f, b7 = 0.f;
                int j = 0;
                for (; j + 1 < nd; j += 2) {
                    uint4 u0 = *(const uint4*)(base + (size_t)lst[j] * 512);
                    uint4 u1 = *(const uint4*)(base + (size_t)lst[j + 1] * 512);
                    b0 += bflo(u0.x) + bflo(u1.x); b1v += bfhi(u0.x) + bfhi(u1.x);
                    b2v += bflo(u0.y) + bflo(u1.y); b3 += bfhi(u0.y) + bfhi(u1.y);
                    b4 += bflo(u0.z) + bflo(u1.z); b5 += bfhi(u0.z) + bfhi(u1.z);
                    b6 += bflo(u0.w) + bflo(u1.w); b7 += bfhi(u0.w) + bfhi(u1.w);
                }
                if (j < nd) {
                    uint4 u0 = *(const uint4*)(base + (size_t)lst[j] * 512);
                    b0 += bflo(u0.x); b1v += bfhi(u0.x);
                    b2v += bflo(u0.y); b3 += bfhi(u0.y);
                    b4 += bflo(u0.z); b5 += bfhi(u0.z);
                    b6 += bflo(u0.w); b7 += bfhi(u0.w);
                }
                float inv = 1.0f / (float)deg;
                a0 += b0 * inv; a1 += b1v * inv; a2 += b2v * inv; a3 += b3 * inv;
                a4 += b4 * inv; a5 += b5 * inv; a6 += b6 * inv; a7 += b7 * inv;
            }
        }
        const float* bt = btab1 + mk * 128 + l * 8;
        float4 t0 = *(const float4*)bt;
        float4 t1 = *(const float4*)(bt + 4);
        uint4 o;
        o.x = pk2(fmaxf(a0 + t0.x, 0.f), fmaxf(a1 + t0.y, 0.f));
        o.y = pk2(fmaxf(a2 + t0.z, 0.f), fmaxf(a3 + t0.w, 0.f));
        o.z = pk2(fmaxf(a4 + t1.x, 0.f), fmaxf(a5 + t1.y, 0.f));
        o.w = pk2(fmaxf(a6 + t1.z, 0.f), fmaxf(a7 + t1.w, 0.f));
        int sw = (nl & 7) << 4;
        *(uint4*)((char*)Al + ((nl * 256 + l * 16) ^ sw)) = o;
    }
    __syncthreads();

    // ---- phase 2: 64x256 MFMA; A from LDS, B from L2-resident W2T
    const int lane = tid & 63;
    const int wv   = tid >> 6;
    const int m    = lane & 15;
    const int q    = lane >> 4;

    bf16x8 af[4];
    {
        int row = wv * 16 + m;
        int sw  = (row & 7) << 4;
        #pragma unroll
        for (int kk = 0; kk < 4; ++kk)
            af[kk] = *(const bf16x8*)((const char*)Al +
                         ((row * 256 + kk * 64 + q * 16) ^ sw));
    }

    #pragma unroll
    for (int cp = 0; cp < 2; ++cp) {
        f32x4 acc[8];
        #pragma unroll
        for (int nt = 0; nt < 8; ++nt) acc[nt] = (f32x4){0.f, 0.f, 0.f, 0.f};
        #pragma unroll
        for (int kk = 0; kk < 4; ++kk) {
            #pragma unroll
            for (int nt = 0; nt < 8; ++nt) {
                bf16x8 bfr = *(const bf16x8*)(W2T +
                    (size_t)(cp * 128 + nt * 16 + m) * 128 + kk * 32 + q * 8);
                acc[nt] = __builtin_amdgcn_mfma_f32_16x16x32_bf16(af[kk], bfr, acc[nt], 0, 0, 0);
            }
        }
        #pragma unroll
        for (int rg = 0; rg < 4; ++rg) {
            int row = n0 + wv * 16 + q * 4 + rg;
            if (row < NN) {
                unsigned short* Hp = H2 + (size_t)row * 256 + cp * 128 + m;
                #pragma unroll
                for (int nt = 0; nt < 8; ++nt)
                    Hp[nt * 16] = f2bf(acc[nt][rg]);
            }
        }
    }
}

// ---------------------------------------------------------------------------
// gather-mean layer 2 (R5 simple form): 8 lanes/node, 128B rows (r*64 cols);
// sum across etypes + btab2[mk] -> out [N,64] fp32 (final output).
__global__ __launch_bounds__(256) void gather_node2(
    const unsigned short* __restrict__ H2, const unsigned short* __restrict__ ssrc2,
    const int* __restrict__ cnt, const float* __restrict__ btab2,
    float* __restrict__ out)
{
    int n = blockIdx.x * 32 + (threadIdx.x >> 3);
    if (n >= NN) return;
    int l = threadIdx.x & 7;
    float a0 = 0.f, a1 = 0.f, a2 = 0.f, a3 = 0.f,
          a4 = 0.f, a5 = 0.f, a6 = 0.f, a7 = 0.f;
    int mk = 0;
    #pragma unroll
    for (int r = 0; r < RR; ++r) {
        int seg = r * NN + n;
        int deg = cnt[seg];
        if (deg <= 0) continue;
        mk |= 1 << r;
        int nd = (deg < CAP) ? deg : CAP;
        const unsigned short* lst  = ssrc2 + (size_t)seg * CAP;
        const unsigned short* base = H2 + r * 64 + l * 8;
        float b0 = 0.f, b1v = 0.f, b2v = 0.f, b3 = 0.f,
              b4 = 0.f, b5 = 0.f, b6 = 0.f, b7 = 0.f;
        int j = 0;
        for (; j + 1 < nd; j += 2) {
            uint4 u0 = *(const uint4*)(base + (size_t)lst[j] * 256);
            uint4 u1 = *(const uint4*)(base + (size_t)lst[j + 1] * 256);
            b0 += bflo(u0.x) + bflo(u1.x); b1v += bfhi(u0.x) + bfhi(u1.x);
            b2v += bflo(u0.y) + bflo(u1.y); b3 += bfhi(u0.y) + bfhi(u1.y);
            b4 += bflo(u0.z) + bflo(u1.z); b5 += bfhi(u0.z) + bfhi(u1.z);
            b6 += bflo(u0.w) + bflo(u1.w); b7 += bfhi(u0.w) + bfhi(u1.w);
        }
        if (j < nd) {
            uint4 u0 = *(const uint4*)(base + (size_t)lst[j] * 256);
            b0 += bflo(u0.x); b1v += bfhi(u0.x);
            b2v += bflo(u0.y); b3 += bfhi(u0.y);
            b4 += bflo(u0.z); b5 += bfhi(u0.z);
            b6 += bflo(u0.w); b7 += bfhi(u0.w);
        }
        float inv = 1.0f / (float)deg;
        a0 += b0 * inv; a1 += b1v * inv; a2 += b2v * inv; a3 += b3 * inv;
        a4 += b4 * inv; a5 += b5 * inv; a6 += b6 * inv; a7 += b7 * inv;
    }
    const float* bt = btab2 + mk * 64 + l * 8;
    float4 t0 = *(const float4*)bt;
    float4 t1 = *(const float4*)(bt + 4);
    float* op = out + (size_t)n * 64 + l * 8;
    *(float4*)op       = make_float4(a0 + t0.x, a1 + t0.y, a2 + t0.z, a3 + t0.w);
    *(float4*)(op + 4) = make_float4(a4 + t1.x, a5 + t1.y, a6 + t1.z, a7 + t1.w);
}

// ---------------------------------------------------------------------------
extern "C" void kernel_launch(void* const* d_in, const int* in_sizes, int n_in,
                              void* d_out, int out_size, void* d_ws, size_t ws_size,
                              hipStream_t stream)
{
    const float* feat  = (const float*)d_in[0];   // [N,128]
    const float* W1    = (const float*)d_in[1];   // [R,128,128]
    const float* b1    = (const float*)d_in[2];   // [R,128]
    const float* W2    = (const float*)d_in[3];   // [R,128,64]
    const float* b2    = (const float*)d_in[4];   // [R,64]
    const int*   edges = (const int*)d_in[5];     // [R,2,E]
    float* out = (float*)d_out;                   // [N,64] fp32

    char* p = (char*)d_ws;
    auto alloc = [&](size_t bytes) { char* q = p; p += (bytes + 255) & ~(size_t)255; return q; };
    int* cnt                 = (int*)alloc((size_t)SC_TOTAL * 4);                  // 0.8MB
    unsigned short* ssrc2    = (unsigned short*)alloc((size_t)SC_TOTAL * CAP * 2); // 12.8MB
    unsigned short* W1T      = (unsigned short*)alloc((size_t)512 * 128 * 2);
    unsigned short* W2T      = (unsigned short*)alloc((size_t)256 * 128 * 2);
    float* btab1             = (float*)alloc((size_t)16 * 128 * 4);
    float* btab2             = (float*)alloc((size_t)16 * 64 * 4);
    unsigned short* featb    = (unsigned short*)alloc((size_t)NN * 128 * 2);   // 12.8MB
    unsigned short* H        = (unsigned short*)alloc((size_t)NN * 512 * 2);   // 51.2MB (H1)
    unsigned short* H2       = (unsigned short*)alloc((size_t)NN * 256 * 2);   // 25.6MB (separate)

    // 1: featb + weight prep + zero cnt (R5 form)
    init_kernel<<<6842, 256, 0, stream>>>(feat, featb, W1, b1, W2, b2,
                                          W1T, W2T, btab1, btab2, cnt);
    // 2: FUSED bucket-append (odd blocks) + H1 = featb @ W1cat (even blocks)
    fill_gemm1<<<NB_G1 + NB_F, 256, 0, stream>>>(edges, cnt, ssrc2, featb, W1T, H);
    // 3: FUSED h1 = relu(mean+btab1) [LDS] -> H2 = h1 @ W2cat  [N,256]
    gather_gemm2<<<(NN + 63) / 64, 256, 0, stream>>>(H, ssrc2, cnt, btab1, W2T, H2);
    // 4: out = sum_r mean_r(H2 slices) + btab2[mk]  [N,64] fp32
    gather_node2<<<(NN + 31) / 32, 256, 0, stream>>>(H2, ssrc2, cnt, btab2, out);
}

// Round 11
// 205.487 us; speedup vs baseline: 1.1441x; 1.1186x over previous
//
#include <hip/hip_runtime.h>

#define NN 50000
#define EE 200000
#define RR 4
#define SC_TOTAL (RR * NN)                 // 200000 segments
#define CAP 32                             // max in-degree per (node,etype); P(exceed)~1e-19
#define GTILE ((NN + 127) / 128)           // 391 row-tiles of 128 for gemm1
#define NB_G1 (4 * GTILE)                  // 1564 gemm1 tiles (512 cols)
#define NB_F  1563                         // fill chunks (512 edges each, 2/thread)

typedef __attribute__((ext_vector_type(8))) short bf16x8;
typedef __attribute__((ext_vector_type(4))) float f32x4;

__device__ inline unsigned short f2bf(float x) {   // round-to-nearest-even
    unsigned int u = __float_as_uint(x);
    u += 0x7fffu + ((u >> 16) & 1u);
    return (unsigned short)(u >> 16);
}
__device__ inline unsigned pk2(float a, float b) {
    return (unsigned)f2bf(a) | ((unsigned)f2bf(b) << 16);
}
__device__ inline float bflo(unsigned u) { return __uint_as_float(u << 16); }
__device__ inline float bfhi(unsigned u) { return __uint_as_float(u & 0xffff0000u); }

// ---------------------------------------------------------------------------
// init (R5 form): featb [0,6250) | W1T [6250,6506) | W2T [6506,6634) |
// btab1 [6634,6642) | btab2 [6642,6646) | cnt zero [6646,6842).
// W layouts are TRANSFORM-FIRST concat: WT[jout][k], jout = r*ON + j.
__global__ __launch_bounds__(256) void init_kernel(
    const float* __restrict__ feat, unsigned short* __restrict__ featb,
    const float* __restrict__ W1, const float* __restrict__ b1,
    const float* __restrict__ W2, const float* __restrict__ b2,
    unsigned short* __restrict__ W1T, unsigned short* __restrict__ W2T,
    float* __restrict__ btab1, float* __restrict__ btab2,
    int* __restrict__ cnt)
{
    int b = blockIdx.x, t = threadIdx.x;
    if (b < 6250) {
        int i = (b * 256 + t) * 4;
        float4 v = *(const float4*)&feat[i];
        *(uint2*)&featb[i] = make_uint2(pk2(v.x, v.y), pk2(v.z, v.w));
    } else if (b < 6506) {
        // W1T[(r*128+j)*128 + k] = W1[r,k,j];  i in [0,65536)
        int i = (b - 6250) * 256 + t;
        int jout = i >> 7, k = i & 127;
        int r = jout >> 7, j = jout & 127;
        W1T[i] = f2bf(W1[r * 16384 + k * 128 + j]);
    } else if (b < 6634) {
        // W2T[(r*64+j)*128 + k] = W2[r,k,j];  i in [0,32768)
        int i = (b - 6506) * 256 + t;
        int jout = i >> 7, k = i & 127;
        int r = jout >> 6, j = jout & 63;
        W2T[i] = f2bf(W2[r * 8192 + k * 64 + j]);
    } else if (b < 6642) {
        int i = (b - 6634) * 256 + t;
        int mm = i >> 7, c = i & 127;
        float s = 0.f;
        #pragma unroll
        for (int r = 0; r < RR; ++r) if (mm & (1 << r)) s += b1[r * 128 + c];
        btab1[i] = s;
    } else if (b < 6646) {
        int i = (b - 6642) * 256 + t;
        int mm = i >> 6, c = i & 63;
        float s = 0.f;
        #pragma unroll
        for (int r = 0; r < RR; ++r) if (mm & (1 << r)) s += b2[r * 64 + c];
        btab2[i] = s;
    } else {
        // zero cnt: 200K ints, int4 per thread
        int i = ((b - 6646) * 256 + t) * 4;
        if (i < SC_TOTAL) *(int4*)&cnt[i] = make_int4(0, 0, 0, 0);
    }
}

// ---------------------------------------------------------------------------
// FUSED fill + gemm1 (R5 exact). Even blocks: one 128x128 tile of
// H1 = featb @ W1cat (W LDS-swizzled). Odd blocks: 512-edge bucket-append
// chunk (TCC-bound). 1:1 interleave -> resident mix hides gemm under scatter.
__global__ __launch_bounds__(256) void fill_gemm1(
    const int* __restrict__ edges, int* __restrict__ cnt,
    unsigned short* __restrict__ ssrc2,
    const unsigned short* __restrict__ A, const unsigned short* __restrict__ WT,
    unsigned short* __restrict__ H)
{
    __shared__ __align__(16) unsigned short Wl[128 * 128];   // 32768 B (gemm path)
    const int bid = blockIdx.x;
    const int tid = threadIdx.x;

    if (bid & 1) {
        // ---- fill path: f in [0, NB_F), 2 edges/thread (independent chains)
        int f = bid >> 1;
        #pragma unroll
        for (int k = 0; k < 2; ++k) {
            int i = f * 512 + k * 256 + tid;
            if (i < RR * EE) {
                int r = i / EE;
                int e = i - r * EE;
                const int* es = edges + (size_t)r * 2 * EE;
                int src = es[e];
                int dst = es[EE + e];
                int seg = r * NN + dst;
                int p = atomicAdd(&cnt[seg], 1);
                if (p < CAP) ssrc2[(size_t)seg * CAP + p] = (unsigned short)src;
            }
        }
        return;
    }

    // ---- gemm path: g in [0, NB_G1); tile (col0, row0), OTOT=512
    const int g    = bid >> 1;
    const int wv   = tid >> 6;
    const int lane = tid & 63;
    const int m    = lane & 15;
    const int q    = lane >> 4;
    const int col0 = (g & 3) * 128;
    const int row0 = (g >> 2) * 128;

    // stage W panel once: linear global read, swizzled LDS write
    #pragma unroll
    for (int i = 0; i < 8; ++i) {
        int L  = i * 4096 + tid * 16;       // linear byte in [128][256]
        int nr = L >> 8, ir = L & 255;
        uint4 v = *(const uint4*)((const char*)WT + ((size_t)(col0 + nr) << 8) + ir);
        *(uint4*)((char*)Wl + nr * 256 + (ir ^ ((nr & 7) << 4))) = v;
    }
    __syncthreads();

    f32x4 acc[2][8];
    #pragma unroll
    for (int rf = 0; rf < 2; ++rf)
        #pragma unroll
        for (int nt = 0; nt < 8; ++nt) acc[rf][nt] = (f32x4){0.f, 0.f, 0.f, 0.f};

    const int ra0 = row0 + wv * 32 + m;
    const int ra1 = ra0 + 16;
    const bool g0 = ra0 < NN, g1 = ra1 < NN;
    const unsigned short* Ap0 = A + (size_t)ra0 * 128 + q * 8;
    const unsigned short* Ap1 = A + (size_t)ra1 * 128 + q * 8;
    const bf16x8 bz = (bf16x8){0, 0, 0, 0, 0, 0, 0, 0};

    #pragma unroll
    for (int kk = 0; kk < 4; ++kk) {
        bf16x8 a0 = g0 ? *(const bf16x8*)(Ap0 + kk * 32) : bz;
        bf16x8 a1 = g1 ? *(const bf16x8*)(Ap1 + kk * 32) : bz;
        #pragma unroll
        for (int nt = 0; nt < 8; ++nt) {
            int offb = (nt * 16 + m) * 256 + ((kk * 64 + q * 16) ^ ((m & 7) << 4));
            bf16x8 bfr = *(const bf16x8*)((const char*)Wl + offb);
            acc[0][nt] = __builtin_amdgcn_mfma_f32_16x16x32_bf16(a0, bfr, acc[0][nt], 0, 0, 0);
            acc[1][nt] = __builtin_amdgcn_mfma_f32_16x16x32_bf16(a1, bfr, acc[1][nt], 0, 0, 0);
        }
    }

    #pragma unroll
    for (int rf = 0; rf < 2; ++rf) {
        #pragma unroll
        for (int rg = 0; rg < 4; ++rg) {
            int row = row0 + wv * 32 + rf * 16 + q * 4 + rg;
            if (row < NN) {
                unsigned short* Hp = H + (size_t)row * 512 + col0 + m;
                #pragma unroll
                for (int nt = 0; nt < 8; ++nt)
                    Hp[nt * 16] = f2bf(acc[rf][nt][rg]);
            }
        }
    }
}

// ---------------------------------------------------------------------------
// gather-mean layer 1 (R5 simple form — BW-bound, keep lean): 16 lanes/node;
// per etype, mean of H1[src, r*128..+128); sum + btab1[mk] + relu -> h1r.
__global__ __launch_bounds__(256) void gather_node1(
    const unsigned short* __restrict__ H1, const unsigned short* __restrict__ ssrc2,
    const int* __restrict__ cnt, const float* __restrict__ btab1,
    unsigned short* __restrict__ h1r)
{
    int n = blockIdx.x * 16 + (threadIdx.x >> 4);
    if (n >= NN) return;
    int l = threadIdx.x & 15;
    float a0 = 0.f, a1 = 0.f, a2 = 0.f, a3 = 0.f,
          a4 = 0.f, a5 = 0.f, a6 = 0.f, a7 = 0.f;
    int mk = 0;
    #pragma unroll
    for (int r = 0; r < RR; ++r) {
        int seg = r * NN + n;
        int deg = cnt[seg];
        if (deg <= 0) continue;
        mk |= 1 << r;
        int nd = (deg < CAP) ? deg : CAP;
        const unsigned short* lst  = ssrc2 + (size_t)seg * CAP;
        const unsigned short* base = H1 + r * 128 + l * 8;
        float b0 = 0.f, b1v = 0.f, b2v = 0.f, b3 = 0.f,
              b4 = 0.f, b5 = 0.f, b6 = 0.f, b7 = 0.f;
        int j = 0;
        for (; j + 1 < nd; j += 2) {
            uint4 u0 = *(const uint4*)(base + (size_t)lst[j] * 512);
            uint4 u1 = *(const uint4*)(base + (size_t)lst[j + 1] * 512);
            b0 += bflo(u0.x) + bflo(u1.x); b1v += bfhi(u0.x) + bfhi(u1.x);
            b2v += bflo(u0.y) + bflo(u1.y); b3 += bfhi(u0.y) + bfhi(u1.y);
            b4 += bflo(u0.z) + bflo(u1.z); b5 += bfhi(u0.z) + bfhi(u1.z);
            b6 += bflo(u0.w) + bflo(u1.w); b7 += bfhi(u0.w) + bfhi(u1.w);
        }
        if (j < nd) {
            uint4 u0 = *(const uint4*)(base + (size_t)lst[j] * 512);
            b0 += bflo(u0.x); b1v += bfhi(u0.x);
            b2v += bflo(u0.y); b3 += bfhi(u0.y);
            b4 += bflo(u0.z); b5 += bfhi(u0.z);
            b6 += bflo(u0.w); b7 += bfhi(u0.w);
        }
        float inv = 1.0f / (float)deg;
        a0 += b0 * inv; a1 += b1v * inv; a2 += b2v * inv; a3 += b3 * inv;
        a4 += b4 * inv; a5 += b5 * inv; a6 += b6 * inv; a7 += b7 * inv;
    }
    const float* bt = btab1 + mk * 128 + l * 8;
    float4 t0 = *(const float4*)bt;
    float4 t1 = *(const float4*)(bt + 4);
    uint4 o;
    o.x = pk2(fmaxf(a0 + t0.x, 0.f), fmaxf(a1 + t0.y, 0.f));
    o.y = pk2(fmaxf(a2 + t0.z, 0.f), fmaxf(a3 + t0.w, 0.f));
    o.z = pk2(fmaxf(a4 + t1.x, 0.f), fmaxf(a5 + t1.y, 0.f));
    o.w = pk2(fmaxf(a6 + t1.z, 0.f), fmaxf(a7 + t1.w, 0.f));
    *(uint4*)&h1r[(size_t)n * 128 + l * 8] = o;
}

// ---------------------------------------------------------------------------
// transform-first GEMM (layer 2): H2[N x 256] = h1r[N x 128]_bf16 @ W2T^T.
template<int OTOT>
__global__ __launch_bounds__(256) void gemm_tf(
    const unsigned short* __restrict__ A, const unsigned short* __restrict__ WT,
    unsigned short* __restrict__ H)
{
    __shared__ __align__(16) unsigned short Wl[128 * 128];   // 32768 B, swizzled
    const int tid  = threadIdx.x;
    const int wv   = tid >> 6;
    const int lane = tid & 63;
    const int m    = lane & 15;
    const int q    = lane >> 4;
    const int col0 = blockIdx.x * 128;
    const int row0 = blockIdx.y * 128;

    #pragma unroll
    for (int i = 0; i < 8; ++i) {
        int L  = i * 4096 + tid * 16;       // linear byte in [128][256]
        int nr = L >> 8, ir = L & 255;
        uint4 v = *(const uint4*)((const char*)WT + ((size_t)(col0 + nr) << 8) + ir);
        *(uint4*)((char*)Wl + nr * 256 + (ir ^ ((nr & 7) << 4))) = v;
    }
    __syncthreads();

    f32x4 acc[2][8];
    #pragma unroll
    for (int rf = 0; rf < 2; ++rf)
        #pragma unroll
        for (int nt = 0; nt < 8; ++nt) acc[rf][nt] = (f32x4){0.f, 0.f, 0.f, 0.f};

    const int ra0 = row0 + wv * 32 + m;
    const int ra1 = ra0 + 16;
    const bool g0 = ra0 < NN, g1 = ra1 < NN;
    const unsigned short* Ap0 = A + (size_t)ra0 * 128 + q * 8;
    const unsigned short* Ap1 = A + (size_t)ra1 * 128 + q * 8;
    const bf16x8 bz = (bf16x8){0, 0, 0, 0, 0, 0, 0, 0};

    #pragma unroll
    for (int kk = 0; kk < 4; ++kk) {
        bf16x8 a0 = g0 ? *(const bf16x8*)(Ap0 + kk * 32) : bz;
        bf16x8 a1 = g1 ? *(const bf16x8*)(Ap1 + kk * 32) : bz;
        #pragma unroll
        for (int nt = 0; nt < 8; ++nt) {
            int offb = (nt * 16 + m) * 256 + ((kk * 64 + q * 16) ^ ((m & 7) << 4));
            bf16x8 bfr = *(const bf16x8*)((const char*)Wl + offb);
            acc[0][nt] = __builtin_amdgcn_mfma_f32_16x16x32_bf16(a0, bfr, acc[0][nt], 0, 0, 0);
            acc[1][nt] = __builtin_amdgcn_mfma_f32_16x16x32_bf16(a1, bfr, acc[1][nt], 0, 0, 0);
        }
    }

    #pragma unroll
    for (int rf = 0; rf < 2; ++rf) {
        #pragma unroll
        for (int rg = 0; rg < 4; ++rg) {
            int row = row0 + wv * 32 + rf * 16 + q * 4 + rg;
            if (row < NN) {
                unsigned short* Hp = H + (size_t)row * OTOT + col0 + m;
                #pragma unroll
                for (int nt = 0; nt < 8; ++nt)
                    Hp[nt * 16] = f2bf(acc[rf][nt][rg]);
            }
        }
    }
}

// ---------------------------------------------------------------------------
// gather-mean layer 2, MLP form (R6-verified): 8 lanes/node; uint4 idx preload
// -> j-outer/r-inner = 4 independent row loads per step (latency-bound fix);
// tail loop for deg>8. Sum + btab2[mk] -> out [N,64] fp32.
__global__ __launch_bounds__(256) void gather_node2(
    const unsigned short* __restrict__ H2, const unsigned short* __restrict__ ssrc2,
    const int* __restrict__ cnt, const float* __restrict__ btab2,
    float* __restrict__ out)
{
    int n = blockIdx.x * 32 + (threadIdx.x >> 3);
    if (n >= NN) return;
    int l = threadIdx.x & 7;

    int   dg[RR];
    uint4 id[RR];
    #pragma unroll
    for (int r = 0; r < RR; ++r) {
        int seg = r * NN + n;
        dg[r] = cnt[seg];
        id[r] = *(const uint4*)(ssrc2 + (size_t)seg * CAP);
    }

    float ac[RR][8];
    #pragma unroll
    for (int r = 0; r < RR; ++r)
        #pragma unroll
        for (int i = 0; i < 8; ++i) ac[r][i] = 0.f;

    #pragma unroll
    for (int j = 0; j < 8; ++j) {
        #pragma unroll
        for (int r = 0; r < RR; ++r) {
            if (j < dg[r]) {
                unsigned w = (j >> 1) == 0 ? id[r].x : (j >> 1) == 1 ? id[r].y
                           : (j >> 1) == 2 ? id[r].z : id[r].w;
                unsigned s = (j & 1) ? (w >> 16) : (w & 0xffffu);
                uint4 u = *(const uint4*)(H2 + r * 64 + l * 8 + (size_t)s * 256);
                ac[r][0] += bflo(u.x); ac[r][1] += bfhi(u.x);
                ac[r][2] += bflo(u.y); ac[r][3] += bfhi(u.y);
                ac[r][4] += bflo(u.z); ac[r][5] += bfhi(u.z);
                ac[r][6] += bflo(u.w); ac[r][7] += bfhi(u.w);
            }
        }
    }
    if ((dg[0] | dg[1] | dg[2] | dg[3]) > 8) {
        #pragma unroll
        for (int r = 0; r < RR; ++r) {
            int nd = dg[r] < CAP ? dg[r] : CAP;
            for (int j = 8; j < nd; ++j) {
                unsigned s = ssrc2[(size_t)(r * NN + n) * CAP + j];
                uint4 u = *(const uint4*)(H2 + r * 64 + l * 8 + (size_t)s * 256);
                ac[r][0] += bflo(u.x); ac[r][1] += bfhi(u.x);
                ac[r][2] += bflo(u.y); ac[r][3] += bfhi(u.y);
                ac[r][4] += bflo(u.z); ac[r][5] += bfhi(u.z);
                ac[r][6] += bflo(u.w); ac[r][7] += bfhi(u.w);
            }
        }
    }

    int mk = (dg[0] > 0 ? 1 : 0) | (dg[1] > 0 ? 2 : 0) |
             (dg[2] > 0 ? 4 : 0) | (dg[3] > 0 ? 8 : 0);
    float iv[RR];
    #pragma unroll
    for (int r = 0; r < RR; ++r) iv[r] = dg[r] > 0 ? 1.0f / (float)dg[r] : 0.f;

    const float* bt = btab2 + mk * 64 + l * 8;
    float4 t0 = *(const float4*)bt;
    float4 t1 = *(const float4*)(bt + 4);
    float o0[8] = {t0.x, t0.y, t0.z, t0.w, t1.x, t1.y, t1.z, t1.w};
    #pragma unroll
    for (int i = 0; i < 8; ++i)
        #pragma unroll
        for (int r = 0; r < RR; ++r) o0[i] += ac[r][i] * iv[r];

    float* op = out + (size_t)n * 64 + l * 8;
    *(float4*)op       = make_float4(o0[0], o0[1], o0[2], o0[3]);
    *(float4*)(op + 4) = make_float4(o0[4], o0[5], o0[6], o0[7]);
}

// ---------------------------------------------------------------------------
extern "C" void kernel_launch(void* const* d_in, const int* in_sizes, int n_in,
                              void* d_out, int out_size, void* d_ws, size_t ws_size,
                              hipStream_t stream)
{
    const float* feat  = (const float*)d_in[0];   // [N,128]
    const float* W1    = (const float*)d_in[1];   // [R,128,128]
    const float* b1    = (const float*)d_in[2];   // [R,128]
    const float* W2    = (const float*)d_in[3];   // [R,128,64]
    const float* b2    = (const float*)d_in[4];   // [R,64]
    const int*   edges = (const int*)d_in[5];     // [R,2,E]
    float* out = (float*)d_out;                   // [N,64] fp32

    char* p = (char*)d_ws;
    auto alloc = [&](size_t bytes) { char* q = p; p += (bytes + 255) & ~(size_t)255; return q; };
    int* cnt                 = (int*)alloc((size_t)SC_TOTAL * 4);                  // 0.8MB
    unsigned short* ssrc2    = (unsigned short*)alloc((size_t)SC_TOTAL * CAP * 2); // 12.8MB
    unsigned short* W1T      = (unsigned short*)alloc((size_t)512 * 128 * 2);
    unsigned short* W2T      = (unsigned short*)alloc((size_t)256 * 128 * 2);
    float* btab1             = (float*)alloc((size_t)16 * 128 * 4);
    float* btab2             = (float*)alloc((size_t)16 * 64 * 4);
    unsigned short* featb    = (unsigned short*)alloc((size_t)NN * 128 * 2);   // 12.8MB
    unsigned short* h1r      = (unsigned short*)alloc((size_t)NN * 128 * 2);   // 12.8MB
    unsigned short* H        = (unsigned short*)alloc((size_t)NN * 512 * 2);   // 51.2MB (H1; reused as H2)

    // 1: featb + weight prep + zero cnt
    init_kernel<<<6842, 256, 0, stream>>>(feat, featb, W1, b1, W2, b2,
                                          W1T, W2T, btab1, btab2, cnt);
    // 2: FUSED bucket-append (odd blocks) + H1 = featb @ W1cat (even blocks)
    fill_gemm1<<<NB_G1 + NB_F, 256, 0, stream>>>(edges, cnt, ssrc2, featb, W1T, H);
    // 3: h1 = relu(sum_r mean_r(H1 slices) + btab1[mk])  [N,128] bf16
    gather_node1<<<(NN + 15) / 16, 256, 0, stream>>>(H, ssrc2, cnt, btab1, h1r);
    // 4: H2 = h1 @ W2cat  [N,256]  (overwrites H; H1 no longer needed)
    gemm_tf<256><<<dim3(2, GTILE), 256, 0, stream>>>(h1r, W2T, H);
    // 5: out = sum_r mean_r(H2 slices) + btab2[mk]  [N,64] fp32
    gather_node2<<<(NN + 31) / 32, 256, 0, stream>>>(H, ssrc2, cnt, btab2, out);
}